// Round 4
// baseline (3351.566 us; speedup 1.0000x reference)
//
#include <hip/hip_runtime.h>
#include <hip/hip_bf16.h>
#include <math.h>

#define SEQ 70
#define HID 230
#define G3  690
#define EMBD 50
#define DIN 60
#define NTOT 2048
#define NREL 100
#define NBAG 64
#define BAGSZ 32
#define PDIM 5
#define MBS 8   // sentences per GRU block

// ---------------- prep kernels ----------------

__global__ void k_zero(float* p, long n) {
    long i = (long)blockIdx.x * 256 + threadIdx.x;
    if (i < n) p[i] = 0.f;
}

__global__ void k_embed(const int* __restrict__ sent, const int* __restrict__ p1,
                        const int* __restrict__ p2,  const float* __restrict__ wemb,
                        const float* __restrict__ t1, const float* __restrict__ t2,
                        float* __restrict__ emb) {
    long idx = (long)blockIdx.x * 256 + threadIdx.x;
    long total = (long)NTOT * SEQ * DIN;
    if (idx >= total) return;
    int nt = (int)(idx / DIN);
    int j  = (int)(idx % DIN);
    float v;
    if (j < EMBD)             v = wemb[(long)sent[nt] * EMBD + j];
    else if (j < EMBD + PDIM) v = t1[p1[nt] * PDIM + (j - EMBD)];
    else                      v = t2[p2[nt] * PDIM + (j - EMBD - PDIM)];
    emb[idx] = v;
}

// in[g*K+k] -> out[k*G+g]
__global__ void k_transpose(const float* __restrict__ in, float* __restrict__ out,
                            int G, int K) {
    int idx = blockIdx.x * 256 + threadIdx.x;
    if (idx >= G * K) return;
    int g = idx / K, k = idx % K;
    out[k * G + g] = in[idx];
}

// ---------------- GRU ----------------
// Thread hh owns hidden unit hh: computes gates r,z,n for MBS sentences in
// registers, combines locally (no gate LDS roundtrip), one barrier/timestep.
// grid = (NTOT/MBS)*2 = 512 blocks; blockIdx.x&1 = direction.
// Both directions atomicAdd into tup (zeroed beforehand) — single buffer,
// ws-footprint identical to the known-good round-1 layout.
__global__ __launch_bounds__(256) void k_gru(
    const float* __restrict__ emb,
    const float* __restrict__ wihT_f, const float* __restrict__ whhT_f,
    const float* __restrict__ bih_f,  const float* __restrict__ bhh_f,
    const float* __restrict__ wihT_b, const float* __restrict__ whhT_b,
    const float* __restrict__ bih_b,  const float* __restrict__ bhh_b,
    float* __restrict__ tup) {

    const bool rev = blockIdx.x & 1;
    const int  n0  = (blockIdx.x >> 1) * MBS;
    const float* wihT = rev ? wihT_b : wihT_f;
    const float* whhT = rev ? whhT_b : whhT_f;
    const float* bih  = rev ? bih_b  : bih_f;
    const float* bhh  = rev ? bhh_b  : bhh_f;
    const int tid = threadIdx.x;

    __shared__ float h_s[2][HID * MBS];   // [buf][k][n]  14720 B
    __shared__ float e_s[2][DIN * MBS];   // [buf][k][n]   3840 B

    for (int i = tid; i < HID * MBS; i += 256) h_s[0][i] = 0.f;

    const int  hh  = tid;
    const bool act = (hh < HID);
    const int  c_r = act ? hh           : 0;
    const int  c_z = act ? (HID + hh)   : 0;
    const int  c_n = act ? (2*HID + hh) : 0;

    const float brz0 = act ? (bih[c_r] + bhh[c_r]) : 0.f;
    const float bzz0 = act ? (bih[c_z] + bhh[c_z]) : 0.f;
    const float bin0 = act ? bih[c_n] : 0.f;
    const float bhn0 = act ? bhh[c_n] : 0.f;

    const float* wir = wihT + c_r;
    const float* wiz = wihT + c_z;
    const float* win = wihT + c_n;
    const float* whr = whhT + c_r;
    const float* whz = whhT + c_z;
    const float* whn = whhT + c_n;

    float hprev[MBS];
#pragma unroll
    for (int n = 0; n < MBS; ++n) hprev[n] = 0.f;

    for (int t = 0; t < SEQ; ++t) {
        const int tt  = rev ? (SEQ - 1 - t) : t;
        const int cur = t & 1, nxt = cur ^ 1;

        // stage emb tile [60][8] for this step (double-buffered)
        if (tid < 120) {
            int n = tid / 15, q = tid - n * 15;
            const float4 v = *(const float4*)&emb[((long)(n0 + n) * SEQ + tt) * DIN + q * 4];
            int k = q * 4;
            e_s[cur][(k + 0) * MBS + n] = v.x;
            e_s[cur][(k + 1) * MBS + n] = v.y;
            e_s[cur][(k + 2) * MBS + n] = v.z;
            e_s[cur][(k + 3) * MBS + n] = v.w;
        }
        __syncthreads();   // the ONE barrier: h_s[cur] (combine t-1) + e_s[cur] visible

        float ar[MBS], az[MBS], ain[MBS], ahn[MBS];
#pragma unroll
        for (int n = 0; n < MBS; ++n) {
            ar[n] = brz0; az[n] = bzz0; ain[n] = bin0; ahn[n] = bhn0;
        }

        // input projection, K = 60
#pragma unroll 4
        for (int k = 0; k < DIN; ++k) {
            float wr = wir[(size_t)k * G3];
            float wz = wiz[(size_t)k * G3];
            float wn = win[(size_t)k * G3];
            const float4* ep = (const float4*)&e_s[cur][k * MBS];
            float4 e0 = ep[0], e1 = ep[1];
            float ev[MBS] = {e0.x, e0.y, e0.z, e0.w, e1.x, e1.y, e1.z, e1.w};
#pragma unroll
            for (int n = 0; n < MBS; ++n) {
                ar[n]  = fmaf(wr, ev[n], ar[n]);
                az[n]  = fmaf(wz, ev[n], az[n]);
                ain[n] = fmaf(wn, ev[n], ain[n]);
            }
        }
        // hidden projection, K = 230 (h_s float4 reads are wave-broadcast, free)
#pragma unroll 5
        for (int k = 0; k < HID; ++k) {
            float wr = whr[(size_t)k * G3];
            float wz = whz[(size_t)k * G3];
            float wn = whn[(size_t)k * G3];
            const float4* hp = (const float4*)&h_s[cur][k * MBS];
            float4 x0 = hp[0], x1 = hp[1];
            float hv[MBS] = {x0.x, x0.y, x0.z, x0.w, x1.x, x1.y, x1.z, x1.w};
#pragma unroll
            for (int n = 0; n < MBS; ++n) {
                ar[n]  = fmaf(wr, hv[n], ar[n]);
                az[n]  = fmaf(wz, hv[n], az[n]);
                ahn[n] = fmaf(wn, hv[n], ahn[n]);
            }
        }

        // register-local combine; publish new h
        if (act) {
            float hnew[MBS];
#pragma unroll
            for (int n = 0; n < MBS; ++n) {
                float r  = 1.f / (1.f + expf(-ar[n]));
                float z  = 1.f / (1.f + expf(-az[n]));
                float nn = tanhf(ain[n] + r * ahn[n]);
                hnew[n] = (1.f - z) * nn + z * hprev[n];
                hprev[n] = hnew[n];
                h_s[nxt][hh * MBS + n] = hnew[n];
            }
#pragma unroll
            for (int n = 0; n < MBS; ++n)
                atomicAdd(&tup[((long)(n0 + n) * SEQ + tt) * HID + hh], hnew[n]);
        }
        // no second barrier: next iteration's barrier separates
        // combine-writes (h_s[nxt]) from GEMM t+1 reads.
    }
}

// ---------------- word-level attention ----------------
__global__ __launch_bounds__(256) void k_wordattn(
    const float* __restrict__ tup, const float* __restrict__ attw,
    const float* __restrict__ sen_a, const float* __restrict__ sen_r,
    float* __restrict__ repre, float* __restrict__ sbuf) {
    const int n = blockIdx.x, tid = threadIdx.x;
    __shared__ float tl[SEQ * HID];   // 64400 B
    __shared__ float sc[SEQ];
    __shared__ float red[4];
    for (int i = tid; i < SEQ * HID; i += 256) tl[i] = tup[(long)n * SEQ * HID + i];
    __syncthreads();
    if (tid < SEQ) {
        float s = 0.f;
        for (int h = 0; h < HID; ++h) s += tanhf(tl[tid * HID + h]) * attw[h];
        sc[tid] = s;
    }
    __syncthreads();
    if (tid == 0) {
        float m = sc[0];
        for (int t = 1; t < SEQ; ++t) m = fmaxf(m, sc[t]);
        float ssum = 0.f;
        for (int t = 0; t < SEQ; ++t) { float e = expf(sc[t] - m); sc[t] = e; ssum += e; }
        float inv = 1.f / ssum;
        for (int t = 0; t < SEQ; ++t) sc[t] *= inv;
    }
    __syncthreads();
    float part = 0.f;
    if (tid < HID) {
        float r = 0.f;
        for (int t = 0; t < SEQ; ++t) r = fmaf(sc[t], tl[t * HID + tid], r);
        float rep = tanhf(r);
        repre[(long)n * HID + tid] = rep;
        part = rep * sen_a[tid] * sen_r[tid];
    }
    for (int off = 32; off; off >>= 1) part += __shfl_down(part, off, 64);
    if ((tid & 63) == 0) red[tid >> 6] = part;
    __syncthreads();
    if (tid == 0) sbuf[n] = red[0] + red[1] + red[2] + red[3];
}

// ---------------- bag attention + logits + loss + prob + acc ----------------
__global__ __launch_bounds__(256) void k_bag(
    const float* __restrict__ repre, const float* __restrict__ sbuf,
    const float* __restrict__ rel, const float* __restrict__ sen_d,
    const float* __restrict__ y, float* __restrict__ out, float* __restrict__ bagloss) {
    const int b = blockIdx.x, tid = threadIdx.x;
    __shared__ float al[BAGSZ];
    __shared__ float ss[HID];
    __shared__ float lg[NREL];
    if (tid == 0) {
        float m = -1e30f;
        for (int i = 0; i < BAGSZ; ++i) m = fmaxf(m, sbuf[b * BAGSZ + i]);
        float s = 0.f;
        for (int i = 0; i < BAGSZ; ++i) { float e = expf(sbuf[b * BAGSZ + i] - m); al[i] = e; s += e; }
        float inv = 1.f / s;
        for (int i = 0; i < BAGSZ; ++i) al[i] *= inv;
    }
    __syncthreads();
    if (tid < HID) {
        float acc = 0.f;
        for (int i = 0; i < BAGSZ; ++i)
            acc = fmaf(al[i], repre[(long)(b * BAGSZ + i) * HID + tid], acc);
        ss[tid] = acc;
    }
    __syncthreads();
    if (tid < NREL) {
        float acc = sen_d[tid];
        for (int h = 0; h < HID; ++h) acc = fmaf(ss[h], rel[tid * HID + h], acc);
        lg[tid] = acc;
    }
    __syncthreads();
    if (tid == 0) {
        float m = -1e30f; int am = 0;
        for (int r = 0; r < NREL; ++r) if (lg[r] > m) { m = lg[r]; am = r; }
        float s = 0.f;
        for (int r = 0; r < NREL; ++r) s += expf(lg[r] - m);
        float inv = 1.f / s;
        float ym = -1e30f; int ay = 0;
        for (int r = 0; r < NREL; ++r) { float yy = y[b * NREL + r]; if (yy > ym) { ym = yy; ay = r; } }
        out[1 + b] = (am == ay) ? 1.f : 0.f;
        float loss = 0.f;
        for (int r = 0; r < NREL; ++r) {
            float l = lg[r], yy = y[b * NREL + r];
            loss += fmaxf(l, 0.f) - l * yy + log1pf(expf(-fabsf(l)));
            out[1 + NBAG + b * NREL + r] = expf(l - m) * inv;
        }
        bagloss[b] = loss / NREL;
    }
}

__global__ void k_final(const float* __restrict__ bagloss, float* __restrict__ out) {
    if (blockIdx.x == 0 && threadIdx.x == 0) {
        float s = 0.f;
        for (int i = 0; i < NBAG; ++i) s += bagloss[i];
        out[0] = s;
    }
}

// ---------------- host launcher ----------------
extern "C" void kernel_launch(void* const* d_in, const int* in_sizes, int n_in,
                              void* d_out, int out_size, void* d_ws, size_t ws_size,
                              hipStream_t stream) {
    const int*   sent   = (const int*)d_in[0];
    const int*   pos1   = (const int*)d_in[1];
    const int*   pos2   = (const int*)d_in[2];
    const float* ybatch = (const float*)d_in[4];
    const float* wemb   = (const float*)d_in[5];
    const float* p1tab  = (const float*)d_in[6];
    const float* p2tab  = (const float*)d_in[7];
    const float* Wih_f  = (const float*)d_in[8];
    const float* Whh_f  = (const float*)d_in[9];
    const float* bih_f  = (const float*)d_in[10];
    const float* bhh_f  = (const float*)d_in[11];
    const float* Wih_b  = (const float*)d_in[12];
    const float* Whh_b  = (const float*)d_in[13];
    const float* bih_b  = (const float*)d_in[14];
    const float* bhh_b  = (const float*)d_in[15];
    const float* attw   = (const float*)d_in[16];
    const float* sen_a  = (const float*)d_in[17];
    const float* sen_r  = (const float*)d_in[18];
    const float* rel    = (const float*)d_in[19];
    const float* sen_d  = (const float*)d_in[20];
    float* out = (float*)d_out;

    float* ws = (float*)d_ws;
    size_t off = 0;
    float* emb    = ws + off; off += (size_t)NTOT * SEQ * DIN;   // same layout as
    float* wihT_f = ws + off; off += (size_t)DIN * G3;           // round 1 (known to
    float* wihT_b = ws + off; off += (size_t)DIN * G3;           // fit in ws_size)
    float* whhT_f = ws + off; off += (size_t)HID * G3;
    float* whhT_b = ws + off; off += (size_t)HID * G3;
    float* tup    = ws + off; off += (size_t)NTOT * SEQ * HID;
    float* repre  = ws + off; off += (size_t)NTOT * HID;
    float* sbuf   = ws + off; off += (size_t)NTOT;
    float* bagloss= ws + off; off += (size_t)NBAG;

    const long tupN = (long)NTOT * SEQ * HID;
    k_zero<<<(int)((tupN + 255) / 256), 256, 0, stream>>>(tup, tupN);

    const long embN = (long)NTOT * SEQ * DIN;
    k_embed<<<(int)((embN + 255) / 256), 256, 0, stream>>>(sent, pos1, pos2, wemb, p1tab, p2tab, emb);

    k_transpose<<<(G3 * DIN + 255) / 256, 256, 0, stream>>>(Wih_f, wihT_f, G3, DIN);
    k_transpose<<<(G3 * DIN + 255) / 256, 256, 0, stream>>>(Wih_b, wihT_b, G3, DIN);
    k_transpose<<<(G3 * HID + 255) / 256, 256, 0, stream>>>(Whh_f, whhT_f, G3, HID);
    k_transpose<<<(G3 * HID + 255) / 256, 256, 0, stream>>>(Whh_b, whhT_b, G3, HID);

    k_gru<<<(NTOT / MBS) * 2, 256, 0, stream>>>(emb,
        wihT_f, whhT_f, bih_f, bhh_f,
        wihT_b, whhT_b, bih_b, bhh_b, tup);

    k_wordattn<<<NTOT, 256, 0, stream>>>(tup, attw, sen_a, sen_r, repre, sbuf);

    k_bag<<<NBAG, 256, 0, stream>>>(repre, sbuf, rel, sen_d, ybatch, out, bagloss);

    k_final<<<1, 64, 0, stream>>>(bagloss, out);
}